// Round 2
// baseline (1196679.199 us; speedup 1.0000x reference)
//
#include <hip/hip_runtime.h>
#include <cstdint>
#include <cstddef>

#define SEQ       32768
#define NT        512
#define START_TAG 510
#define END_TAG   511
#define NEGF      -10000.0f
#define KCH       64
#define NCH       (SEQ / KCH)   /* 512 chunks */

/* workspace layout (16B aligned)
   bp   : 32 MiB  backpointers (u16)
   M    : 512 KiB chunk-composed maps
   bd   : 2 KiB   chunk boundary tags
   trS  : 2 MiB   per-row descending-sorted (value,index), layout [rank][row]  */
#define BP_BYTES  ((size_t)SEQ * NT * sizeof(unsigned short))
#define M_BYTES   ((size_t)NCH * NT * sizeof(unsigned short))
#define BD_BYTES  ((size_t)NCH * sizeof(int))
#define TRS_OFF   (BP_BYTES + M_BYTES + BD_BYTES)

/* ---------- kernel 1: per-row descending bitonic sort of trans ----------
   trS[r*NT + j] = (float bits of r-th largest of row j, its column index)   */
__global__ __launch_bounds__(NT) void sort_rows_k(const float* __restrict__ tr,
                                                  uint2* __restrict__ trS) {
    __shared__ float sv[NT];
    __shared__ int   si[NT];
    const int j = blockIdx.x;
    const int t = threadIdx.x;
    sv[t] = tr[(size_t)j * NT + t];
    si[t] = t;
    __syncthreads();
    for (int k = 2; k <= NT; k <<= 1) {
        for (int m = k >> 1; m > 0; m >>= 1) {
            const int p = t ^ m;
            if (p > t) {
                const bool desc = ((t & k) == 0);
                const float a = sv[t], b = sv[p];
                const bool sw = desc ? (a < b) : (a > b);
                if (sw) {
                    sv[t] = b; sv[p] = a;
                    const int ia = si[t]; si[t] = si[p]; si[p] = ia;
                }
            }
            __syncthreads();
        }
    }
    /* thread t holds rank-t (largest first); write rank-major, row-contiguous */
    trS[(size_t)t * NT + j] = make_uint2(__float_as_uint(sv[t]), (unsigned)si[t]);
}

/* ---------- kernel 2: single-workgroup pruned Viterbi forward pass ---------- */
__global__ __launch_bounds__(1024) void viterbi_fwd(const float* __restrict__ u,
                                                    const float* __restrict__ tr,
                                                    const uint2* __restrict__ trS,
                                                    unsigned short* __restrict__ bp,
                                                    unsigned short* __restrict__ M,
                                                    int* __restrict__ boundary,
                                                    float* __restrict__ out) {
    __shared__ float alphas[2][NT];
    __shared__ float pval[2][NT];
    __shared__ int   pidx[2][NT];
    __shared__ unsigned short Rbuf[2][NT];
    __shared__ float wmax[8];      /* per-wave max of new alphas (tid<512 waves) */
    __shared__ float wv[16];
    __shared__ int   wi[16];

    const int tid  = threadIdx.x;
    const int j    = tid & (NT - 1);
    const int half = tid >> 9;           /* 0: even ranks, 1: odd ranks */

    if (tid < NT) alphas[0][tid] = (tid == START_TAG) ? 0.0f : NEGF;
    if (tid < 8)  wmax[tid] = 0.0f;      /* max of initial alphas is exactly 0 */
    __syncthreads();

    int cur = 0;
    float ureg = 0.0f, unext = 0.0f;
    if (tid < NT) ureg = u[tid];

    const uint2* tcol = trS + j;

    for (int t = 0; t < SEQ; ++t) {
        if (tid < NT && (t + 1) < SEQ) unext = u[(size_t)(t + 1) * NT + tid];

        /* upper bound on alphas (exact max, written at end of previous step) */
        float amax = wmax[0];
        #pragma unroll
        for (int w = 1; w < 8; ++w) amax = fmaxf(amax, wmax[w]);

        const float* ac = alphas[cur];

        /* pruned scan over this row's candidates in descending tr order.
           Skip-safe: fp add is monotone, so fl(ac[i]+v) <= fl(amax+v); break
           only when fl(amax+v) < bv (strict) => skipped can't win or tie.   */
        float bv = -INFINITY; int bi = 0x7fffffff;
        uint2 e = tcol[(size_t)half << 9];
        for (int r = half; r < NT; r += 2) {
            const int rn = (r + 2 < NT) ? (r + 2) : r;
            const uint2 en = tcol[(size_t)rn << 9];      /* one-ahead prefetch */
            const float v = __uint_as_float(e.x);
            if (amax + v < bv) break;
            const int   i = (int)e.y;
            const float s = ac[i] + v;
            if (s > bv)                { bv = s; bi = i; }
            else if (s == bv && i < bi){ bi = i; }
            e = en;
        }
        pval[half][j] = bv; pidx[half][j] = bi;
        __syncthreads();

        if (tid < NT) {
            /* merge even/odd halves, tie -> lower index */
            const float b0 = pval[0][tid]; const int i0 = pidx[0][tid];
            const float b1 = pval[1][tid]; const int i1 = pidx[1][tid];
            float bvv; int bii;
            if (b1 > b0 || (b1 == b0 && i1 < i0)) { bvv = b1; bii = i1; }
            else                                  { bvv = b0; bii = i0; }

            bp[(size_t)t * NT + tid] = (unsigned short)bii;

            unsigned short rn;
            if ((t & (KCH - 1)) == 0) rn = (unsigned short)bii;
            else                      rn = Rbuf[(t ^ 1) & 1][bii];
            Rbuf[t & 1][tid] = rn;
            if ((t & (KCH - 1)) == (KCH - 1))
                M[(size_t)(t / KCH) * NT + tid] = rn;

            const float na = bvv + ureg;     /* fl(vit + u_t[j]) as reference */
            alphas[cur ^ 1][tid] = na;

            /* per-wave exact max of new alphas -> wmax (no extra barrier) */
            float m = na;
            #pragma unroll
            for (int off = 32; off > 0; off >>= 1)
                m = fmaxf(m, __shfl_down(m, off));
            if ((tid & 63) == 0) wmax[tid >> 6] = m;

            ureg = unext;
        }
        cur ^= 1;
        __syncthreads();
    }

    /* terminal: alphas_T + tr[END_TAG,:], argmax lowest-index tie-break */
    float tv = -INFINITY; int ti = 0x7fffffff;
    if (tid < NT) { tv = alphas[cur][tid] + tr[(size_t)END_TAG * NT + tid]; ti = tid; }
    for (int off = 32; off > 0; off >>= 1) {
        const float ov = __shfl_down(tv, off);
        const int   oi = __shfl_down(ti, off);
        if (ov > tv || (ov == tv && oi < ti)) { tv = ov; ti = oi; }
    }
    const int wid = tid >> 6;
    if ((tid & 63) == 0) { wv[wid] = tv; wi[wid] = ti; }
    __syncthreads();

    if (tid == 0) {
        float bvv = wv[0]; int bii = wi[0];
        for (int w = 1; w < 16; ++w)
            if (wv[w] > bvv || (wv[w] == bvv && wi[w] < bii)) { bvv = wv[w]; bii = wi[w]; }
        out[SEQ] = bvv;                 /* path_score */
        __threadfence();
        int tag = bii;                  /* path[32767] */
        boundary[NCH - 1] = tag;
        for (int c = NCH - 1; c >= 1; --c) {
            tag = (int)M[(size_t)c * NT + tag];
            boundary[c - 1] = tag;
        }
    }
}

/* ---------- kernel 3: 512 independent per-chunk local tracebacks ---------- */
__global__ __launch_bounds__(64) void traceback_k(const unsigned short* __restrict__ bp,
                                                  const int* __restrict__ boundary,
                                                  float* __restrict__ out) {
    if (threadIdx.x != 0) return;
    const int c    = blockIdx.x;
    int       tag  = boundary[c];            /* = path[(c+1)K - 1] */
    const int tend = (c + 1) * KCH - 1;
    out[tend] = (float)tag;
    for (int t = tend - 1; t >= c * KCH; --t) {
        tag = (int)bp[(size_t)(t + 1) * NT + tag];
        out[t] = (float)tag;
    }
}

extern "C" void kernel_launch(void* const* d_in, const int* in_sizes, int n_in,
                              void* d_out, int out_size, void* d_ws, size_t ws_size,
                              hipStream_t stream) {
    const float* unary = (const float*)d_in[0];   /* (32768,1,512) f32 */
    const float* trans = (const float*)d_in[1];   /* (1,512,512)   f32 */
    float* out = (float*)d_out;                   /* [0..32767]=path, [32768]=score */
    char*  ws  = (char*)d_ws;

    unsigned short* bp       = (unsigned short*)ws;
    unsigned short* M        = (unsigned short*)(ws + BP_BYTES);
    int*            boundary = (int*)(ws + BP_BYTES + M_BYTES);
    uint2*          trS      = (uint2*)(ws + TRS_OFF);
    (void)in_sizes; (void)n_in; (void)out_size; (void)ws_size;

    sort_rows_k<<<NT, NT, 0, stream>>>(trans, trS);
    viterbi_fwd<<<1, 1024, 0, stream>>>(unary, trans, trS, bp, M, boundary, out);
    traceback_k<<<NCH, 64, 0, stream>>>(bp, boundary, out);
}

// Round 3
// 932405.176 us; speedup vs baseline: 1.2834x; 1.2834x over previous
//
#include <hip/hip_runtime.h>
#include <cstdint>
#include <cstddef>

#define SEQ       32768
#define NT        512
#define START_TAG 510
#define END_TAG   511
#define NEGF      -10000.0f
#define KCH       64
#define NCH       (SEQ / KCH)   /* 512 chunks */
#define R_FIX     32            /* always-scanned top ranks per row */

/* workspace layout (identical to round 2 — proven to fit)
   bp   : 32 MiB  backpointers (u16)
   M    : 512 KiB chunk-composed maps
   bd   : 2 KiB   chunk boundary tags
   trS  : 2 MiB   per-row descending-sorted (value,index), rank-major [rank][row] */
#define BP_BYTES  ((size_t)SEQ * NT * sizeof(unsigned short))
#define M_BYTES   ((size_t)NCH * NT * sizeof(unsigned short))
#define BD_BYTES  ((size_t)NCH * sizeof(int))
#define TRS_OFF   (BP_BYTES + M_BYTES + BD_BYTES)

/* ---------- kernel 1: per-row descending bitonic sort of trans ----------
   trS[r*NT + j] = (float bits of r-th largest of row j, its column index)   */
__global__ __launch_bounds__(NT) void sort_rows_k(const float* __restrict__ tr,
                                                  uint2* __restrict__ trS) {
    __shared__ float sv[NT];
    __shared__ int   si[NT];
    const int j = blockIdx.x;
    const int t = threadIdx.x;
    sv[t] = tr[(size_t)j * NT + t];
    si[t] = t;
    __syncthreads();
    for (int k = 2; k <= NT; k <<= 1) {
        for (int m = k >> 1; m > 0; m >>= 1) {
            const int p = t ^ m;
            if (p > t) {
                const bool desc = ((t & k) == 0);
                const float a = sv[t], b = sv[p];
                const bool sw = desc ? (a < b) : (a > b);
                if (sw) {
                    sv[t] = b; sv[p] = a;
                    const int ia = si[t]; si[t] = si[p]; si[p] = ia;
                }
            }
            __syncthreads();
        }
    }
    trS[(size_t)t * NT + j] = make_uint2(__float_as_uint(sv[t]), (unsigned)si[t]);
}

/* ---------- kernel 2: single-workgroup chunk-pruned Viterbi forward ---------- */
__global__ __launch_bounds__(1024) void viterbi_fwd(const float* __restrict__ u,
                                                    const float* __restrict__ tr,
                                                    const uint2* __restrict__ trS,
                                                    unsigned short* __restrict__ bp,
                                                    unsigned short* __restrict__ M,
                                                    int* __restrict__ boundary,
                                                    float* __restrict__ out) {
    __shared__ float alphas[2][NT];
    __shared__ float pval[2][NT];
    __shared__ int   pidx[2][NT];
    __shared__ float vcut[NT];               /* value at rank 31 per row */
    __shared__ unsigned short Rbuf[2][NT];   /* composed backptr map */
    __shared__ float wmax[8];
    __shared__ float wv[16];
    __shared__ int   wi[16];

    const int tid   = threadIdx.x;
    const int j     = tid & (NT - 1);
    const int h     = tid >> 9;              /* 0: ranks 0..15, 1: ranks 16..31 */
    const int rbase = h << 4;
    const uint2* tcol = trS + j;

    if (tid < NT) alphas[0][tid] = (tid == START_TAG) ? 0.0f : NEGF;
    if (tid < 8)  wmax[tid] = 0.0f;          /* exact max of initial alphas */
    __syncthreads();

    int cur = 0;
    float ureg = 0.0f, unext = 0.0f;
    if (tid < NT) ureg = u[tid];

    for (int t = 0; t < SEQ; ++t) {
        if (tid < NT && (t + 1) < SEQ) unext = u[(size_t)(t + 1) * NT + tid];

        float amax = wmax[0];
        #pragma unroll
        for (int w = 1; w < 8; ++w) amax = fmaxf(amax, wmax[w]);

        const float* ac = alphas[cur];

        /* ---- fixed top-32 scan: 16 independent lane-coalesced loads ---- */
        uint2 e[16];
        #pragma unroll
        for (int k = 0; k < 16; ++k) e[k] = tcol[(size_t)(rbase + k) << 9];
        float bv = -INFINITY; int bi = 0x7fffffff;
        #pragma unroll
        for (int k = 0; k < 16; ++k) {
            const float v = __uint_as_float(e[k].x);
            const int   i = (int)e[k].y;
            const float s = ac[i] + v;
            if (s > bv || (s == bv && i < bi)) { bv = s; bi = i; }
        }
        pval[h][j] = bv; pidx[h][j] = bi;
        if (h) vcut[j] = __uint_as_float(e[15].x);   /* rank-31 value */
        __syncthreads();

        if (tid < NT) {
            /* merge halves, tie -> lower index */
            const float b0 = pval[0][tid]; const int i0 = pidx[0][tid];
            const float b1 = pval[1][tid]; const int i1 = pidx[1][tid];
            float bvv; int bii;
            if (b1 > b0 || (b1 == b0 && i1 < i0)) { bvv = b1; bii = i1; }
            else                                  { bvv = b0; bii = i0; }

            /* ---- certified continuation (rare): chunks of 16, prune
               check only between chunks. Skip-safe: fl monotone =>
               fl(ac[i]+v) <= fl(amax+vlast) < bvv rules out win AND tie. */
            float vlast = vcut[tid];
            int r = R_FIX;
            while (!(amax + vlast < bvv) && r < NT) {
                uint2 f[16];
                #pragma unroll
                for (int k = 0; k < 16; ++k) f[k] = tcol[(size_t)(r + k) << 9];
                #pragma unroll
                for (int k = 0; k < 16; ++k) {
                    const float v = __uint_as_float(f[k].x);
                    const int   i = (int)f[k].y;
                    const float s = ac[i] + v;
                    if (s > bvv || (s == bvv && i < bii)) { bvv = s; bii = i; }
                }
                vlast = __uint_as_float(f[15].x);
                r += 16;
            }

            bp[(size_t)t * NT + tid] = (unsigned short)bii;

            unsigned short rn;
            if ((t & (KCH - 1)) == 0) rn = (unsigned short)bii;
            else                      rn = Rbuf[(t ^ 1) & 1][bii];
            Rbuf[t & 1][tid] = rn;
            if ((t & (KCH - 1)) == (KCH - 1))
                M[(size_t)(t / KCH) * NT + tid] = rn;

            const float na = bvv + ureg;     /* fl(vit + u_t[j]) as reference */
            alphas[cur ^ 1][tid] = na;

            float m = na;
            #pragma unroll
            for (int off = 32; off > 0; off >>= 1)
                m = fmaxf(m, __shfl_down(m, off));
            if ((tid & 63) == 0) wmax[tid >> 6] = m;

            ureg = unext;
        }
        cur ^= 1;
        __syncthreads();
    }

    /* terminal: alphas_T + tr[END_TAG,:], argmax lowest-index tie-break */
    float tv = -INFINITY; int ti = 0x7fffffff;
    if (tid < NT) { tv = alphas[cur][tid] + tr[(size_t)END_TAG * NT + tid]; ti = tid; }
    for (int off = 32; off > 0; off >>= 1) {
        const float ov = __shfl_down(tv, off);
        const int   oi = __shfl_down(ti, off);
        if (ov > tv || (ov == tv && oi < ti)) { tv = ov; ti = oi; }
    }
    const int wid = tid >> 6;
    if ((tid & 63) == 0) { wv[wid] = tv; wi[wid] = ti; }
    __syncthreads();

    if (tid == 0) {
        float bvv = wv[0]; int bii = wi[0];
        for (int w = 1; w < 16; ++w)
            if (wv[w] > bvv || (wv[w] == bvv && wi[w] < bii)) { bvv = wv[w]; bii = wi[w]; }
        out[SEQ] = bvv;                 /* path_score */
        __threadfence();
        int tag = bii;                  /* path[32767] */
        boundary[NCH - 1] = tag;
        for (int c = NCH - 1; c >= 1; --c) {
            tag = (int)M[(size_t)c * NT + tag];
            boundary[c - 1] = tag;
        }
    }
}

/* ---------- kernel 3: 512 independent per-chunk local tracebacks ---------- */
__global__ __launch_bounds__(64) void traceback_k(const unsigned short* __restrict__ bp,
                                                  const int* __restrict__ boundary,
                                                  float* __restrict__ out) {
    if (threadIdx.x != 0) return;
    const int c    = blockIdx.x;
    int       tag  = boundary[c];            /* = path[(c+1)K - 1] */
    const int tend = (c + 1) * KCH - 1;
    out[tend] = (float)tag;
    for (int t = tend - 1; t >= c * KCH; --t) {
        tag = (int)bp[(size_t)(t + 1) * NT + tag];
        out[t] = (float)tag;
    }
}

extern "C" void kernel_launch(void* const* d_in, const int* in_sizes, int n_in,
                              void* d_out, int out_size, void* d_ws, size_t ws_size,
                              hipStream_t stream) {
    const float* unary = (const float*)d_in[0];   /* (32768,1,512) f32 */
    const float* trans = (const float*)d_in[1];   /* (1,512,512)   f32 */
    float* out = (float*)d_out;                   /* [0..32767]=path, [32768]=score */
    char*  ws  = (char*)d_ws;

    unsigned short* bp       = (unsigned short*)ws;
    unsigned short* M        = (unsigned short*)(ws + BP_BYTES);
    int*            boundary = (int*)(ws + BP_BYTES + M_BYTES);
    uint2*          trS      = (uint2*)(ws + TRS_OFF);
    (void)in_sizes; (void)n_in; (void)out_size; (void)ws_size;

    sort_rows_k<<<NT, NT, 0, stream>>>(trans, trS);
    viterbi_fwd<<<1, 1024, 0, stream>>>(unary, trans, trS, bp, M, boundary, out);
    traceback_k<<<NCH, 64, 0, stream>>>(bp, boundary, out);
}

// Round 4
// 102982.776 us; speedup vs baseline: 11.6202x; 9.0540x over previous
//
#include <hip/hip_runtime.h>
#include <cstdint>
#include <cstddef>

#define SEQ       32768
#define NT        512
#define START_TAG 510
#define END_TAG   511
#define NEGF      -10000.0f
#define KCH       64
#define NCH       (SEQ / KCH)   /* 512 chunks */
#define W         8             /* forward workgroups */
#define ROWS      (NT / W)      /* 64 rows per WG */

/* workspace layout (all 64B aligned)
   bp    : 32 MiB  backpointers (u16)
   M     : 512 KiB chunk-composed maps
   bd    : 2 KiB   chunk boundary tags
   trT   : 1 MiB   transposed transitions (i-major)
   Aglob : 4 KiB   alpha ping-pong, agent-coherent
   flags : 512 B   per-WG progress flags (64B-padded)                       */
#define BP_BYTES  ((size_t)SEQ * NT * sizeof(unsigned short))
#define M_OFF     (BP_BYTES)
#define M_BYTES   ((size_t)NCH * NT * sizeof(unsigned short))
#define BD_OFF    (M_OFF + M_BYTES)
#define BD_BYTES  ((size_t)NCH * sizeof(int))
#define TRT_OFF   (BD_OFF + BD_BYTES)
#define TRT_BYTES ((size_t)NT * NT * sizeof(float))
#define AG_OFF    (TRT_OFF + TRT_BYTES)
#define AG_BYTES  ((size_t)2 * NT * sizeof(float))
#define FL_OFF    (AG_OFF + AG_BYTES)

/* ---------- kernel 0: init alpha_0 + flags ---------- */
__global__ __launch_bounds__(NT) void init_k(float* Ag, int* flags) {
    const int t = threadIdx.x;
    Ag[t]      = (t == START_TAG) ? 0.0f : NEGF;   /* alpha_0, buffer 0 */
    Ag[NT + t] = NEGF;                             /* buffer 1, don't care */
    if (t < W) flags[t * 16] = 0;
}

/* ---------- kernel 1: transpose trans (512x512), i-major ---------- */
__global__ __launch_bounds__(1024) void transpose_k(const float* __restrict__ tr,
                                                    float* __restrict__ trT) {
    __shared__ float tile[32][33];
    const int bx = blockIdx.x * 32, by = blockIdx.y * 32;
    const int tx = threadIdx.x, ty = threadIdx.y;
    tile[ty][tx] = tr[(size_t)(by + ty) * NT + (bx + tx)];
    __syncthreads();
    trT[(size_t)(bx + ty) * NT + (by + tx)] = tile[tx][ty];
}

/* ---------- kernel 2: W-workgroup slice-parallel dense Viterbi forward ----------
   WG w owns output rows [w*64, w*64+64). Wave wv scans i-chunk [wv*32, wv*32+32).
   Alpha exchanged through L3 via agent-scope (sc1) atomics; per-WG flag with
   RELEASE ordering. No acquire fences in the loop -> per-XCD L2 (trT slice)
   stays resident.                                                             */
__global__ __launch_bounds__(1024) void viterbi_fwd(const float* __restrict__ u,
                                                    const float* __restrict__ trT,
                                                    unsigned short* __restrict__ bp,
                                                    float* Ag,
                                                    int* flags) {
    __shared__ float ac[2][NT];          /* alpha ping-pong (per-step buffer) */
    __shared__ float pval[16][ROWS];
    __shared__ int   pidx[16][ROWS];

    const int tid  = threadIdx.x;
    const int w    = (int)blockIdx.x;
    const int j0   = w * ROWS;
    const int lane = tid & 63;
    const int wv   = tid >> 6;           /* 16 waves */
    const int ib   = wv * 32;            /* this wave's i-chunk base */

    for (int t = 0; t < SEQ; ++t) {
        const int buf = t & 1;

        /* prefetch own u slice early (consumed after b3) */
        float uval = 0.0f;
        if (wv == 0) uval = u[(size_t)t * NT + j0 + lane];

        /* per-slice gated alpha fetch: wave k waits only for slice k.
           Own slice (k == w) was written to LDS directly by last merge. */
        if (wv < W && wv != w) {
            while (__hip_atomic_load(&flags[wv * 16], __ATOMIC_RELAXED,
                                     __HIP_MEMORY_SCOPE_AGENT) < t) {}
            const float a = __hip_atomic_load(&Ag[buf * NT + wv * 64 + lane],
                                              __ATOMIC_RELAXED, __HIP_MEMORY_SCOPE_AGENT);
            ac[buf][wv * 64 + lane] = a;
        }
        if (t == 0 && wv == w) {         /* step 0: own slice from init buffer */
            ac[0][wv * 64 + lane] = __hip_atomic_load(&Ag[wv * 64 + lane],
                                          __ATOMIC_RELAXED, __HIP_MEMORY_SCOPE_AGENT);
        }
        __syncthreads();                                   /* b2 */

        /* dense partial scan: 32 candidates, ascending i, strict '>' =>
           lowest index wins ties (jnp.argmax semantics) */
        const float* acb = ac[buf];
        const float* tp  = trT + (size_t)ib * NT + j0 + lane;
        float bv = -INFINITY; int bi = 0;
        #pragma unroll 8
        for (int k = 0; k < 32; ++k) {
            const float s = acb[ib + k] + tp[(size_t)k * NT];
            if (s > bv) { bv = s; bi = ib + k; }
        }
        pval[wv][lane] = bv; pidx[wv][lane] = bi;
        __syncthreads();                                   /* b3 */

        if (wv == 0) {
            /* merge 16 chunks in ascending-i order, keep-first on ties */
            float bvv = pval[0][lane]; int bii = pidx[0][lane];
            #pragma unroll
            for (int c = 1; c < 16; ++c) {
                const float v = pval[c][lane];
                if (v > bvv) { bvv = v; bii = pidx[c][lane]; }
            }
            bp[(size_t)t * NT + j0 + lane] = (unsigned short)bii;

            const float na = bvv + uval;                   /* fl(vit + u_t[j]) */
            ac[buf ^ 1][j0 + lane] = na;                   /* own slice, local */
            __hip_atomic_store(&Ag[(buf ^ 1) * NT + j0 + lane], na,
                               __ATOMIC_RELAXED, __HIP_MEMORY_SCOPE_AGENT);
            if (lane == 0)                                 /* release orders the
                                                              wave's Ag stores */
                __hip_atomic_store(&flags[w * 16], t + 1,
                                   __ATOMIC_RELEASE, __HIP_MEMORY_SCOPE_AGENT);
        }
    }
}

/* ---------- kernel 3: parallel chunk-map composition from bp ---------- */
__global__ __launch_bounds__(NT) void mbuild_k(const unsigned short* __restrict__ bp,
                                               unsigned short* __restrict__ M) {
    __shared__ unsigned short R[2][NT];
    const int c = (int)blockIdx.x, j = threadIdx.x;
    const size_t base = (size_t)c * KCH * NT;
    R[0][j] = bp[base + j];
    int cb = 0;
    for (int t = 1; t < KCH; ++t) {
        const unsigned short r = bp[base + (size_t)t * NT + j];
        __syncthreads();
        R[cb ^ 1][j] = R[cb][r];
        cb ^= 1;
    }
    __syncthreads();
    M[(size_t)c * NT + j] = R[cb][j];
}

/* ---------- kernel 4: terminal argmax + chunk-boundary chase ---------- */
__global__ __launch_bounds__(NT) void chase_k(const float* __restrict__ Ag,
                                              const float* __restrict__ tr,
                                              const unsigned short* __restrict__ M,
                                              int* __restrict__ boundary,
                                              float* __restrict__ out) {
    __shared__ float sv[NT];
    __shared__ int   si[NT];
    const int j = threadIdx.x;
    sv[j] = Ag[j] + tr[(size_t)END_TAG * NT + j];   /* Ag buffer 0 = alpha_SEQ */
    si[j] = j;
    __syncthreads();
    for (int off = NT / 2; off > 0; off >>= 1) {
        if (j < off) {
            const float a = sv[j], b = sv[j + off];
            if (b > a || (b == a && si[j + off] < si[j])) { sv[j] = b; si[j] = si[j + off]; }
        }
        __syncthreads();
    }
    if (j == 0) {
        out[SEQ] = sv[0];                 /* path_score */
        int tag = si[0];                  /* path[32767] */
        boundary[NCH - 1] = tag;
        for (int c = NCH - 1; c >= 1; --c) {
            tag = (int)M[(size_t)c * NT + tag];
            boundary[c - 1] = tag;
        }
    }
}

/* ---------- kernel 5: 512 independent per-chunk local tracebacks ---------- */
__global__ __launch_bounds__(64) void traceback_k(const unsigned short* __restrict__ bp,
                                                  const int* __restrict__ boundary,
                                                  float* __restrict__ out) {
    if (threadIdx.x != 0) return;
    const int c    = (int)blockIdx.x;
    int       tag  = boundary[c];            /* = path[(c+1)K - 1] */
    const int tend = (c + 1) * KCH - 1;
    out[tend] = (float)tag;
    for (int t = tend - 1; t >= c * KCH; --t) {
        tag = (int)bp[(size_t)(t + 1) * NT + tag];
        out[t] = (float)tag;
    }
}

extern "C" void kernel_launch(void* const* d_in, const int* in_sizes, int n_in,
                              void* d_out, int out_size, void* d_ws, size_t ws_size,
                              hipStream_t stream) {
    const float* unary = (const float*)d_in[0];   /* (32768,1,512) f32 */
    const float* trans = (const float*)d_in[1];   /* (1,512,512)   f32 */
    float* out = (float*)d_out;                   /* [0..32767]=path, [32768]=score */
    char*  ws  = (char*)d_ws;

    unsigned short* bp       = (unsigned short*)ws;
    unsigned short* M        = (unsigned short*)(ws + M_OFF);
    int*            boundary = (int*)(ws + BD_OFF);
    float*          trT      = (float*)(ws + TRT_OFF);
    float*          Ag       = (float*)(ws + AG_OFF);
    int*            flags    = (int*)(ws + FL_OFF);
    (void)in_sizes; (void)n_in; (void)out_size; (void)ws_size;

    init_k<<<1, NT, 0, stream>>>(Ag, flags);
    transpose_k<<<dim3(16, 16), dim3(32, 32), 0, stream>>>(trans, trT);
    viterbi_fwd<<<W, 1024, 0, stream>>>(unary, trT, bp, Ag, flags);
    mbuild_k<<<NCH, NT, 0, stream>>>(bp, M);
    chase_k<<<1, NT, 0, stream>>>(Ag, trans, M, boundary, out);
    traceback_k<<<NCH, 64, 0, stream>>>(bp, boundary, out);
}